// Round 2
// baseline (92.907 us; speedup 1.0000x reference)
//
#include <hip/hip_runtime.h>

// GCN B=2, N=8192, F=64, O=64 — all fp32 (reference dtype).
// adj[b,i,j] = si[b,i] + sj[b,j] + c is rank-structured, so:
//   deg[b,i]  = N*(si_i + c) + SjT[b],   d = rsqrt(max(deg,1))
//   out[b,i,o]= relu( d_i*((si_i+c)*U[b,o] + V[b,o]) + bias_o )
//   U[b,:] = (sum_j d_j   * x[b,j,:]) @ W
//   V[b,:] = (sum_j sj_j*d_j * x[b,j,:]) @ W
// Total work O(B*N*F): read x twice, write out once.

#define NN 8192
#define FF 64

// K1: per-row sj (x.w_j), si (x.w_i). 16 rows/block, 16 threads/row, float4.
__global__ __launch_bounds__(256) void k_sisj(const float* __restrict__ x,
                                              const float* __restrict__ adj_w,
                                              float* __restrict__ si,
                                              float* __restrict__ sj,
                                              float* __restrict__ SjT) {
    __shared__ float wj[FF], wi[FF];
    __shared__ float red[16];
    int tid = threadIdx.x;
    if (tid < 2 * FF) {
        float v = adj_w[tid];
        if (tid < FF) wj[tid] = v; else wi[tid - FF] = v;
    }
    __syncthreads();
    int q = tid & 15;             // float4 index within row
    int rloc = tid >> 4;          // 0..15
    int row = blockIdx.x * 16 + rloc;
    float4 xv  = reinterpret_cast<const float4*>(x + (size_t)row * FF)[q];
    float4 wjv = reinterpret_cast<const float4*>(wj)[q];
    float4 wiv = reinterpret_cast<const float4*>(wi)[q];
    float a = xv.x * wjv.x + xv.y * wjv.y + xv.z * wjv.z + xv.w * wjv.w;
    float b = xv.x * wiv.x + xv.y * wiv.y + xv.z * wiv.z + xv.w * wiv.w;
    #pragma unroll
    for (int s = 8; s; s >>= 1) {           // reduce 16 contiguous lanes
        a += __shfl_down(a, s, 16);
        b += __shfl_down(b, s, 16);
    }
    if (q == 0) { sj[row] = a; si[row] = b; red[rloc] = a; }
    __syncthreads();
    if (tid == 0) {
        float t = 0.f;
        #pragma unroll
        for (int i = 0; i < 16; ++i) t += red[i];
        atomicAdd(SjT + (blockIdx.x >> 9), t);   // 512 blocks per batch
    }
}

// K2: p[b,f] += d_j*x[j,f]; q[b,f] += sj_j*d_j*x[j,f]. 128 rows/block, lane=col.
__global__ __launch_bounds__(256) void k_pq(const float* __restrict__ x,
                                            const float* __restrict__ adj_b,
                                            const float* __restrict__ si,
                                            const float* __restrict__ sj,
                                            const float* __restrict__ SjT,
                                            float* __restrict__ p,
                                            float* __restrict__ q) {
    int tid = threadIdx.x;
    int c = tid & 63, g = tid >> 6;
    int batch = blockIdx.x >> 6;                 // 64 blocks/batch
    int base = batch * NN + (blockIdx.x & 63) * 128;
    float cadj = adj_b[0];
    float sjt = SjT[batch];
    float pa = 0.f, qa = 0.f;
    for (int r = g; r < 128; r += 4) {
        int row = base + r;
        float siv = si[row];
        float sjv = sj[row];
        float deg = 8192.f * (siv + cadj) + sjt;
        float d = rsqrtf(fmaxf(deg, 1.f));
        float xv = x[(size_t)row * FF + c];
        pa += d * xv;
        qa += sjv * d * xv;
    }
    __shared__ float ps[256], qs[256];
    ps[tid] = pa; qs[tid] = qa;
    __syncthreads();
    if (tid < 64) {
        float psum = ps[tid] + ps[tid + 64] + ps[tid + 128] + ps[tid + 192];
        float qsum = qs[tid] + qs[tid + 64] + qs[tid + 128] + qs[tid + 192];
        atomicAdd(p + batch * 64 + tid, psum);
        atomicAdd(q + batch * 64 + tid, qsum);
    }
}

// K3: U = p@W, V = q@W. 2 batches x {U,V} x 64 outputs = 256 threads.
__global__ __launch_bounds__(256) void k_uv(const float* __restrict__ weight,
                                            const float* __restrict__ p,
                                            const float* __restrict__ q,
                                            float* __restrict__ U,
                                            float* __restrict__ V) {
    int tid = threadIdx.x;
    int b = tid >> 7, sel = (tid >> 6) & 1, o = tid & 63;
    const float* src = sel ? q : p;
    float s = 0.f;
    #pragma unroll
    for (int f = 0; f < FF; ++f)
        s += src[b * 64 + f] * weight[f * 64 + o];
    (sel ? V : U)[b * 64 + o] = s;
}

// K4: epilogue, float4 stores. 16 rows/block, 16 threads/row.
__global__ __launch_bounds__(256) void k_out(const float* __restrict__ adj_b,
                                             const float* __restrict__ bias,
                                             const float* __restrict__ si,
                                             const float* __restrict__ SjT,
                                             const float* __restrict__ U,
                                             const float* __restrict__ V,
                                             float* __restrict__ out) {
    int tid = threadIdx.x;
    int q = tid & 15;
    int rloc = tid >> 4;
    int row = blockIdx.x * 16 + rloc;            // 1024 blocks
    int batch = row >> 13;                       // row/8192
    float cadj = adj_b[0];
    float sjt = SjT[batch];
    float siv = si[row];
    float deg = 8192.f * (siv + cadj) + sjt;
    float d = rsqrtf(fmaxf(deg, 1.f));
    float a = d * (siv + cadj);
    float4 Uv = reinterpret_cast<const float4*>(U + batch * 64)[q];
    float4 Vv = reinterpret_cast<const float4*>(V + batch * 64)[q];
    float4 bv = reinterpret_cast<const float4*>(bias)[q];
    float4 o;
    o.x = fmaxf(a * Uv.x + d * Vv.x + bv.x, 0.f);
    o.y = fmaxf(a * Uv.y + d * Vv.y + bv.y, 0.f);
    o.z = fmaxf(a * Uv.z + d * Vv.z + bv.z, 0.f);
    o.w = fmaxf(a * Uv.w + d * Vv.w + bv.w, 0.f);
    reinterpret_cast<float4*>(out + (size_t)row * FF)[q] = o;
}

extern "C" void kernel_launch(void* const* d_in, const int* in_sizes, int n_in,
                              void* d_out, int out_size, void* d_ws, size_t ws_size,
                              hipStream_t stream) {
    const float* x      = (const float*)d_in[0];   // (2,8192,64)
    const float* adj_w  = (const float*)d_in[1];   // (128,)
    const float* adj_b  = (const float*)d_in[2];   // (1,)
    const float* weight = (const float*)d_in[3];   // (64,64)
    const float* bias   = (const float*)d_in[4];   // (64,)
    float* out = (float*)d_out;                    // (2,8192,64)

    float* ws  = (float*)d_ws;
    float* si  = ws;                // 16384 floats
    float* sj  = ws + 16384;        // 16384
    float* SjT = ws + 32768;        // 2
    float* p   = ws + 32832;        // 128
    float* q   = ws + 32960;        // 128
    float* U   = ws + 33088;        // 128
    float* V   = ws + 33216;        // 128

    // zero the atomic accumulators (SjT, p, q) — ws is poisoned 0xAA
    hipMemsetAsync(ws + 32768, 0, (33088 - 32768) * sizeof(float), stream);

    k_sisj<<<1024, 256, 0, stream>>>(x, adj_w, si, sj, SjT);
    k_pq  <<<128, 256, 0, stream>>>(x, adj_b, si, sj, SjT, p, q);
    k_uv  <<<1, 256, 0, stream>>>(weight, p, q, U, V);
    k_out <<<1024, 256, 0, stream>>>(adj_b, bias, si, SjT, U, V, out);
}